// Round 1
// baseline (2089.256 us; speedup 1.0000x reference)
//
#include <hip/hip_runtime.h>
#include <math.h>

#define N_NODES 50000
#define N_EDGES 800000

// ---------------------------------------------------------------------------
// Generic tiled GEMM: out[M,N] = act(A[M,K](lda) @ W[K,N] + bias), N in {64,128}
// BM=32 rows/block, 256 threads, K chunked by 64, W+A staged in LDS.
// ACT: 0=none, 1=relu. BIAS: add bias[col] before act.
// ---------------------------------------------------------------------------
template<int K, int N, int ACT, bool BIAS>
__global__ __launch_bounds__(256) void gemm_kernel(
    const float* __restrict__ A, int lda,
    const float* __restrict__ W,
    const float* __restrict__ bias,
    float* __restrict__ out, int ldo, int M)
{
    constexpr int BM = 32, BK = 64;
    constexpr int RPT = BM * N / 256;           // rows per thread
    constexpr int NCH = (K + BK - 1) / BK;      // K chunks
    __shared__ float sW[BK * N];
    __shared__ float sA[BM * BK];
    const int tid  = threadIdx.x;
    const int brow = blockIdx.x * BM;
    const int col  = tid & (N - 1);
    const int rbase = (tid / N) * RPT;

    float acc[RPT];
#pragma unroll
    for (int r = 0; r < RPT; ++r) acc[r] = 0.f;

    for (int ch = 0; ch < NCH; ++ch) {
        const int k0 = ch * BK;
        // stage W chunk [BK x N] (coalesced)
        for (int i = tid; i < BK * N; i += 256) {
            int kk = i / N, c = i % N;
            int gk = k0 + kk;
            sW[i] = (gk < K) ? W[gk * N + c] : 0.f;
        }
        // stage A chunk [BM x BK] (coalesced)
        for (int i = tid; i < BM * BK; i += 256) {
            int r = i >> 6, c = i & 63;
            int gr = brow + r, gk = k0 + c;
            sA[i] = (gr < M && gk < K) ? A[(size_t)gr * lda + gk] : 0.f;
        }
        __syncthreads();
#pragma unroll
        for (int k = 0; k < BK; ++k) {
            float w = sW[k * N + col];
#pragma unroll
            for (int r = 0; r < RPT; ++r)
                acc[r] = fmaf(sA[(rbase + r) * BK + k], w, acc[r]);
        }
        __syncthreads();
    }

    float b = 0.f;
    if (BIAS) b = bias[col];
#pragma unroll
    for (int r = 0; r < RPT; ++r) {
        int gr = brow + rbase + r;
        if (gr < M) {
            float v = acc[r] + b;
            if (ACT == 1) v = fmaxf(v, 0.f);
            out[(size_t)gr * ldo + col] = v;
        }
    }
}

// ---------------------------------------------------------------------------
// out[r*ldo + c] = bias[c] for r < n, c < D   (pre-init for scatter-add)
// ---------------------------------------------------------------------------
template<int D>
__global__ __launch_bounds__(256) void init_bias_kernel(
    float* __restrict__ out, int ldo, const float* __restrict__ bias, int n)
{
    int i = blockIdx.x * 256 + threadIdx.x;
    if (i < n * D) {
        int r = i / D, c = i % D;   // D is power of 2 -> shifts
        out[(size_t)r * ldo + c] = bias[c];
    }
}

// ---------------------------------------------------------------------------
// agg[dst[e]][:] += h[src[e]][:]  via f32 atomics; one wave per edge.
// ---------------------------------------------------------------------------
template<int D>
__global__ __launch_bounds__(256) void scatter_kernel(
    const float* __restrict__ h, int ldh,
    const int* __restrict__ src, const int* __restrict__ dst,
    float* __restrict__ agg, int ldo, int ne)
{
    const int lane = threadIdx.x & 63;
    const int wid  = blockIdx.x * 4 + (threadIdx.x >> 6);
    const int nw   = gridDim.x * 4;
    for (int e = wid; e < ne; e += nw) {
        int s = src[e], d = dst[e];
        const float* hp = h   + (size_t)s * ldh;
        float*       ap = agg + (size_t)d * ldo;
#pragma unroll
        for (int j = lane; j < D; j += 64)
            atomicAdd(&ap[j], hp[j]);
    }
}

// ---------------------------------------------------------------------------
// Final: out = sigmoid([X | X1 | X2] @ W2 + b2), K=448 (64+128+256), N=50
// Same tile structure; A staged per-chunk from the right source buffer.
// ---------------------------------------------------------------------------
__global__ __launch_bounds__(256) void final_kernel(
    const float* __restrict__ X,    // [M,64]
    const float* __restrict__ X1,   // [M,128]
    const float* __restrict__ X2,   // [M,256]
    const float* __restrict__ W2,   // [448,50]
    const float* __restrict__ b2,   // [50]
    float* __restrict__ out, int M)
{
    constexpr int BM = 32, BK = 64, NC = 50;
    __shared__ float sW[BK * 64];
    __shared__ float sA[BM * BK];
    const int tid  = threadIdx.x;
    const int brow = blockIdx.x * BM;
    const int col  = tid & 63;
    const int rbase = (tid >> 6) * 8;

    float acc[8];
#pragma unroll
    for (int r = 0; r < 8; ++r) acc[r] = 0.f;

    for (int ch = 0; ch < 7; ++ch) {
        const float* Ap; int lda, off;
        if (ch == 0)     { Ap = X;  lda = 64;  off = 0; }
        else if (ch < 3) { Ap = X1; lda = 128; off = (ch - 1) * 64; }
        else             { Ap = X2; lda = 256; off = (ch - 3) * 64; }

        for (int i = tid; i < BK * 64; i += 256) {
            int kk = i >> 6, c = i & 63;
            int gk = ch * 64 + kk;
            sW[i] = (c < NC) ? W2[gk * NC + c] : 0.f;
        }
        for (int i = tid; i < BM * BK; i += 256) {
            int r = i >> 6, c = i & 63;
            int gr = brow + r;
            sA[i] = (gr < M) ? Ap[(size_t)gr * lda + off + c] : 0.f;
        }
        __syncthreads();
#pragma unroll
        for (int k = 0; k < BK; ++k) {
            float w = sW[k * 64 + col];
#pragma unroll
            for (int r = 0; r < 8; ++r)
                acc[r] = fmaf(sA[(rbase + r) * BK + k], w, acc[r]);
        }
        __syncthreads();
    }

    if (col < NC) {
        float b = b2[col];
#pragma unroll
        for (int r = 0; r < 8; ++r) {
            int gr = brow + rbase + r;
            if (gr < M)
                out[(size_t)gr * NC + col] = 1.f / (1.f + expf(-(acc[r] + b)));
        }
    }
}

// ---------------------------------------------------------------------------
extern "C" void kernel_launch(void* const* d_in, const int* in_sizes, int n_in,
                              void* d_out, int out_size, void* d_ws, size_t ws_size,
                              hipStream_t stream)
{
    const float* features = (const float*)d_in[0];
    const int*   ei       = (const int*)d_in[1];
    const float* W1  = (const float*)d_in[2];
    const float* b1  = (const float*)d_in[3];
    const float* Wc1 = (const float*)d_in[4];
    const float* bc1 = (const float*)d_in[5];
    const float* Wc2 = (const float*)d_in[6];
    const float* bc2 = (const float*)d_in[7];
    const float* W2  = (const float*)d_in[8];
    const float* b2  = (const float*)d_in[9];
    float* out = (float*)d_out;

    const int* src = ei;            // edge_index[0]
    const int* dst = ei + N_EDGES;  // edge_index[1]

    // workspace layout (floats)
    float* X  = (float*)d_ws;                 // [N,64]
    float* X1 = X  + (size_t)N_NODES * 64;    // [N,128] = concat(x11,x12)
    float* X2 = X1 + (size_t)N_NODES * 128;   // [N,256] = concat(x21,x22)
    float* H  = X2 + (size_t)N_NODES * 256;   // [N,128] scratch (GEMM output pre-scatter)

    const int MB = (N_NODES + 31) / 32;       // 1563 row-tiles
    const int IB64  = (N_NODES * 64  + 255) / 256;
    const int IB128 = (N_NODES * 128 + 255) / 256;
    const int SB = 4096;                      // scatter blocks (grid-stride)

    // x = relu(features @ W1 + b1)
    gemm_kernel<500, 64, 1, true><<<MB, 256, 0, stream>>>(features, 500, W1, b1, X, 64, N_NODES);

    // x11 = scatter(x @ Wc1) + bc1  -> X1[:, 0:64]
    gemm_kernel<64, 64, 0, false><<<MB, 256, 0, stream>>>(X, 64, Wc1, nullptr, H, 64, N_NODES);
    init_bias_kernel<64><<<IB64, 256, 0, stream>>>(X1, 128, bc1, N_NODES);
    scatter_kernel<64><<<SB, 256, 0, stream>>>(H, 64, src, dst, X1, 128, N_EDGES);

    // x12 = scatter(x11 @ Wc1) + bc1 -> X1[:, 64:128]
    gemm_kernel<64, 64, 0, false><<<MB, 256, 0, stream>>>(X1, 128, Wc1, nullptr, H, 64, N_NODES);
    init_bias_kernel<64><<<IB64, 256, 0, stream>>>(X1 + 64, 128, bc1, N_NODES);
    scatter_kernel<64><<<SB, 256, 0, stream>>>(H, 64, src, dst, X1 + 64, 128, N_EDGES);

    // x21 = scatter(x1 @ Wc2) + bc2 -> X2[:, 0:128]
    gemm_kernel<128, 128, 0, false><<<MB, 256, 0, stream>>>(X1, 128, Wc2, nullptr, H, 128, N_NODES);
    init_bias_kernel<128><<<IB128, 256, 0, stream>>>(X2, 256, bc2, N_NODES);
    scatter_kernel<128><<<SB, 256, 0, stream>>>(H, 128, src, dst, X2, 256, N_EDGES);

    // x22 = scatter(x21 @ Wc2) + bc2 -> X2[:, 128:256]
    gemm_kernel<128, 128, 0, false><<<MB, 256, 0, stream>>>(X2, 256, Wc2, nullptr, H, 128, N_NODES);
    init_bias_kernel<128><<<IB128, 256, 0, stream>>>(X2 + 128, 256, bc2, N_NODES);
    scatter_kernel<128><<<SB, 256, 0, stream>>>(H, 128, src, dst, X2 + 128, 256, N_EDGES);

    // out = sigmoid([X | X1 | X2] @ W2 + b2)
    final_kernel<<<MB, 256, 0, stream>>>(X, X1, X2, W2, b2, out, N_NODES);
}

// Round 2
// 1469.607 us; speedup vs baseline: 1.4216x; 1.4216x over previous
//
#include <hip/hip_runtime.h>
#include <math.h>

#define N_NODES 50000
#define N_EDGES 800000

// ---------------------------------------------------------------------------
// Generic tiled GEMM: out[M,N] = act(A[M,K](lda) @ W[K,N] + bias[col])
// BM=32 rows/block, 256 threads, K chunked by 64, W+A staged in LDS.
// ACT: 0=none, 1=relu.
// ---------------------------------------------------------------------------
template<int K, int N, int ACT>
__global__ __launch_bounds__(256) void gemm_kernel(
    const float* __restrict__ A, int lda,
    const float* __restrict__ W,
    const float* __restrict__ bias,
    float* __restrict__ out, int ldo, int M)
{
    constexpr int BM = 32, BK = 64;
    constexpr int RPT = BM * N / 256;           // rows per thread
    constexpr int NCH = (K + BK - 1) / BK;      // K chunks
    __shared__ float sW[BK * N];
    __shared__ float sA[BM * BK];
    const int tid  = threadIdx.x;
    const int brow = blockIdx.x * BM;
    const int col  = tid & (N - 1);
    const int rbase = (tid / N) * RPT;

    float acc[RPT];
#pragma unroll
    for (int r = 0; r < RPT; ++r) acc[r] = 0.f;

    for (int ch = 0; ch < NCH; ++ch) {
        const int k0 = ch * BK;
        for (int i = tid; i < BK * N; i += 256) {
            int kk = i / N, c = i % N;
            int gk = k0 + kk;
            sW[i] = (gk < K) ? W[gk * N + c] : 0.f;
        }
        for (int i = tid; i < BM * BK; i += 256) {
            int r = i >> 6, c = i & 63;
            int gr = brow + r, gk = k0 + c;
            sA[i] = (gr < M && gk < K) ? A[(size_t)gr * lda + gk] : 0.f;
        }
        __syncthreads();
#pragma unroll
        for (int k = 0; k < BK; ++k) {
            float w = sW[k * N + col];
#pragma unroll
            for (int r = 0; r < RPT; ++r)
                acc[r] = fmaf(sA[(rbase + r) * BK + k], w, acc[r]);
        }
        __syncthreads();
    }

    float b = bias[col];
#pragma unroll
    for (int r = 0; r < RPT; ++r) {
        int gr = brow + rbase + r;
        if (gr < M) {
            float v = acc[r] + b;
            if (ACT == 1) v = fmaxf(v, 0.f);
            out[(size_t)gr * ldo + col] = v;
        }
    }
}

// ---------------------------------------------------------------------------
// CSR build: zero counts -> histogram dst -> exclusive scan -> fill lists
// ---------------------------------------------------------------------------
__global__ __launch_bounds__(256) void zero_kernel(int* __restrict__ p, int n)
{
    int i = blockIdx.x * 256 + threadIdx.x;
    if (i < n) p[i] = 0;
}

__global__ __launch_bounds__(256) void count_kernel(
    const int* __restrict__ dst, int* __restrict__ counts, int ne)
{
    int e = blockIdx.x * 256 + threadIdx.x;
    if (e < ne) atomicAdd(&counts[dst[e]], 1);
}

// single block, 1024 threads: exclusive scan of counts[0..n) -> row_ptr, cursor
__global__ __launch_bounds__(1024) void scan_kernel(
    const int* __restrict__ counts, int* __restrict__ row_ptr,
    int* __restrict__ cursor, int n)
{
    __shared__ int sdata[1024];
    const int t = threadIdx.x;
    const int C = (n + 1023) / 1024;
    const int lo = t * C, hi = min(lo + C, n);
    int s = 0;
    for (int i = lo; i < hi; ++i) s += counts[i];
    sdata[t] = s;
    __syncthreads();
    for (int off = 1; off < 1024; off <<= 1) {
        int v = (t >= off) ? sdata[t - off] : 0;
        __syncthreads();
        sdata[t] += v;
        __syncthreads();
    }
    int run = sdata[t] - s;   // exclusive prefix
    for (int i = lo; i < hi; ++i) {
        int c = counts[i];
        row_ptr[i] = run;
        cursor[i]  = run;
        run += c;
    }
    if (t == 1023) row_ptr[n] = sdata[1023];
}

__global__ __launch_bounds__(256) void fill_kernel(
    const int* __restrict__ src, const int* __restrict__ dst,
    int* __restrict__ cursor, int* __restrict__ elist, int ne)
{
    int e = blockIdx.x * 256 + threadIdx.x;
    if (e < ne) {
        int p = atomicAdd(&cursor[dst[e]], 1);
        elist[p] = src[e];
    }
}

// ---------------------------------------------------------------------------
// Gather aggregation: out[i][:] = sum_{e in CSR(i)} h[elist[e]][:]
// One wave per node; lane = column (D=64) or 2 columns (D=128).
// ---------------------------------------------------------------------------
template<int D>
__global__ __launch_bounds__(256) void agg_kernel(
    const float* __restrict__ h, int ldh,
    const int* __restrict__ row_ptr, const int* __restrict__ elist,
    float* __restrict__ out, int ldo, int n)
{
    const int lane = threadIdx.x & 63;
    const int node = blockIdx.x * 4 + (threadIdx.x >> 6);
    if (node >= n) return;
    const int beg = row_ptr[node], end = row_ptr[node + 1];
    float a0 = 0.f, a1 = 0.f, b0 = 0.f, b1 = 0.f;
    int e = beg;
    for (; e + 1 < end; e += 2) {
        int s0 = elist[e], s1 = elist[e + 1];
        const float* p0 = h + (size_t)s0 * ldh;
        const float* p1 = h + (size_t)s1 * ldh;
        a0 += p0[lane];
        b0 += p1[lane];
        if (D == 128) { a1 += p0[lane + 64]; b1 += p1[lane + 64]; }
    }
    if (e < end) {
        int s0 = elist[e];
        const float* p0 = h + (size_t)s0 * ldh;
        a0 += p0[lane];
        if (D == 128) a1 += p0[lane + 64];
    }
    float* q = out + (size_t)node * ldo;
    q[lane] = a0 + b0;
    if (D == 128) q[lane + 64] = a1 + b1;
}

// ---------------------------------------------------------------------------
// Final: out = sigmoid([X | X1 | X2] @ W2 + b2), K=448 (64+128+256), N=50
// ---------------------------------------------------------------------------
__global__ __launch_bounds__(256) void final_kernel(
    const float* __restrict__ X,    // [M,64]
    const float* __restrict__ X1,   // [M,128]
    const float* __restrict__ X2,   // [M,256]
    const float* __restrict__ W2,   // [448,50]
    const float* __restrict__ b2,   // [50]
    float* __restrict__ out, int M)
{
    constexpr int BM = 32, BK = 64, NC = 50;
    __shared__ float sW[BK * 64];
    __shared__ float sA[BM * BK];
    const int tid  = threadIdx.x;
    const int brow = blockIdx.x * BM;
    const int col  = tid & 63;
    const int rbase = (tid >> 6) * 8;

    float acc[8];
#pragma unroll
    for (int r = 0; r < 8; ++r) acc[r] = 0.f;

    for (int ch = 0; ch < 7; ++ch) {
        const float* Ap; int lda, off;
        if (ch == 0)     { Ap = X;  lda = 64;  off = 0; }
        else if (ch < 3) { Ap = X1; lda = 128; off = (ch - 1) * 64; }
        else             { Ap = X2; lda = 256; off = (ch - 3) * 64; }

        for (int i = tid; i < BK * 64; i += 256) {
            int kk = i >> 6, c = i & 63;
            int gk = ch * 64 + kk;
            sW[i] = (c < NC) ? W2[gk * NC + c] : 0.f;
        }
        for (int i = tid; i < BM * BK; i += 256) {
            int r = i >> 6, c = i & 63;
            int gr = brow + r;
            sA[i] = (gr < M) ? Ap[(size_t)gr * lda + off + c] : 0.f;
        }
        __syncthreads();
#pragma unroll
        for (int k = 0; k < BK; ++k) {
            float w = sW[k * 64 + col];
#pragma unroll
            for (int r = 0; r < 8; ++r)
                acc[r] = fmaf(sA[(rbase + r) * BK + k], w, acc[r]);
        }
        __syncthreads();
    }

    if (col < NC) {
        float b = b2[col];
#pragma unroll
        for (int r = 0; r < 8; ++r) {
            int gr = brow + rbase + r;
            if (gr < M)
                out[(size_t)gr * NC + col] = 1.f / (1.f + expf(-(acc[r] + b)));
        }
    }
}

// ---------------------------------------------------------------------------
extern "C" void kernel_launch(void* const* d_in, const int* in_sizes, int n_in,
                              void* d_out, int out_size, void* d_ws, size_t ws_size,
                              hipStream_t stream)
{
    const float* features = (const float*)d_in[0];
    const int*   ei       = (const int*)d_in[1];
    const float* W1  = (const float*)d_in[2];
    const float* b1  = (const float*)d_in[3];
    const float* Wc1 = (const float*)d_in[4];
    const float* bc1 = (const float*)d_in[5];
    const float* Wc2 = (const float*)d_in[6];
    const float* bc2 = (const float*)d_in[7];
    const float* W2  = (const float*)d_in[8];
    const float* b2  = (const float*)d_in[9];
    float* out = (float*)d_out;

    const int* src = ei;            // edge_index[0]
    const int* dst = ei + N_EDGES;  // edge_index[1]

    // workspace layout
    float* X  = (float*)d_ws;                 // [N,64]   x
    float* X1 = X  + (size_t)N_NODES * 64;    // [N,128]  concat(x11,x12)
    float* X2 = X1 + (size_t)N_NODES * 128;   // [N,256]  concat(x21,x22)
    // G = aggregation scratch, aliased onto X2[:,128:256] (safe: see notes)
    float* G  = X2 + 128;                     // [N,<=128] with ld 256
    int* counts  = (int*)(X2 + (size_t)N_NODES * 256);
    int* cursor  = counts + N_NODES;
    int* row_ptr = cursor + N_NODES;          // [N+1]
    int* elist   = row_ptr + (N_NODES + 1);   // [E]

    const int MB = (N_NODES + 31) / 32;       // 1563 row-tiles
    const int EB = (N_EDGES + 255) / 256;     // 3125 edge blocks
    const int NB = (N_NODES + 255) / 256;     // 196
    const int AB = (N_NODES + 3) / 4;         // 12500 agg blocks

    // ---- CSR build (dst-sorted incoming edge lists) ----
    zero_kernel<<<NB, 256, 0, stream>>>(counts, N_NODES);
    count_kernel<<<EB, 256, 0, stream>>>(dst, counts, N_EDGES);
    scan_kernel<<<1, 1024, 0, stream>>>(counts, row_ptr, cursor, N_NODES);
    fill_kernel<<<EB, 256, 0, stream>>>(src, dst, cursor, elist, N_EDGES);

    // ---- x = relu(features @ W1 + b1) ----
    gemm_kernel<500, 64, 1><<<MB, 256, 0, stream>>>(features, 500, W1, b1, X, 64, N_NODES);

    // ---- x11 = A(x) @ Wc1 + bc1 ----
    agg_kernel<64><<<AB, 256, 0, stream>>>(X, 64, row_ptr, elist, G, 256, N_NODES);
    gemm_kernel<64, 64, 0><<<MB, 256, 0, stream>>>(G, 256, Wc1, bc1, X1, 128, N_NODES);

    // ---- x12 = A(x11) @ Wc1 + bc1 ;  keep G11 = A(x11) for x21 ----
    agg_kernel<64><<<AB, 256, 0, stream>>>(X1, 128, row_ptr, elist, G, 256, N_NODES);
    gemm_kernel<64, 64, 0><<<MB, 256, 0, stream>>>(G, 256, Wc1, bc1, X1 + 64, 128, N_NODES);

    // ---- G12 = A(x12) ;  x21 = [G11|G12] @ Wc2 + bc2 ----
    agg_kernel<64><<<AB, 256, 0, stream>>>(X1 + 64, 128, row_ptr, elist, G + 64, 256, N_NODES);
    gemm_kernel<128, 128, 0><<<MB, 256, 0, stream>>>(G, 256, Wc2, bc2, X2, 256, N_NODES);

    // ---- G21 = A(x21) ;  x22 = G21 @ Wc2 + bc2 (in-place region, safe) ----
    agg_kernel<128><<<AB, 256, 0, stream>>>(X2, 256, row_ptr, elist, G, 256, N_NODES);
    gemm_kernel<128, 128, 0><<<MB, 256, 0, stream>>>(G, 256, Wc2, bc2, X2 + 128, 256, N_NODES);

    // ---- out = sigmoid([X | X1 | X2] @ W2 + b2) ----
    final_kernel<<<MB, 256, 0, stream>>>(X, X1, X2, W2, b2, out, N_NODES);
}

// Round 4
// 749.849 us; speedup vs baseline: 2.7862x; 1.9599x over previous
//
#include <hip/hip_runtime.h>
#include <math.h>

#define N_NODES 50000
#define N_EDGES 800000

// ---------------------------------------------------------------------------
// Register-tiled GEMM: out[M, 64*gridDim.y] = act(A[M,K](lda) @ W[K,ldw] + bias)
// BM=64, BN=64, BK=32, 256 threads = 16x16, 4x4 micro-tile per thread.
// Inner loop: per k-quad, 4+4 ds_read_b128 feed 64 FMAs -> VALU-bound.
// ACT: 0=none, 1=relu.
// ---------------------------------------------------------------------------
template<int K, int ACT>
__global__ __launch_bounds__(256) void gemm_rt_kernel(
    const float* __restrict__ A, int lda,
    const float* __restrict__ W, int ldw,
    const float* __restrict__ bias,
    float* __restrict__ out, int ldo, int M)
{
    constexpr int BM = 64, BK = 32;
    constexpr int SAS = 36;                     // sA row stride (pad 32->36)
    constexpr int NCH = (K + BK - 1) / BK;
    __shared__ float sA[BM * SAS];
    __shared__ float sW[BK * 64];
    const int tid  = threadIdx.x;
    const int brow = blockIdx.x * BM;
    const int n0   = blockIdx.y * 64;
    const int tn4  = (tid & 15) * 4;
    const int tm4  = (tid >> 4) * 4;

    float acc[4][4];
#pragma unroll
    for (int i = 0; i < 4; ++i)
#pragma unroll
        for (int j = 0; j < 4; ++j) acc[i][j] = 0.f;

    for (int ch = 0; ch < NCH; ++ch) {
        const int k0 = ch * BK;
        // stage W chunk [BK x 64]: 2048 floats = 512 float4, 2 per thread
#pragma unroll
        for (int i = 0; i < 2; ++i) {
            int f = i * 256 + tid;
            int kk = f >> 4, c4 = (f & 15) * 4;
            int gk = k0 + kk;
            float4 v = make_float4(0.f, 0.f, 0.f, 0.f);
            if (gk < K) v = *(const float4*)&W[(size_t)gk * ldw + n0 + c4];
            *(float4*)&sW[kk * 64 + c4] = v;
        }
        // stage A chunk [BM x BK]: 2048 floats = 512 float4, 2 per thread
#pragma unroll
        for (int i = 0; i < 2; ++i) {
            int f = i * 256 + tid;
            int r = f >> 3, c4 = (f & 7) * 4;
            int gr = brow + r, gk = k0 + c4;
            float4 v = make_float4(0.f, 0.f, 0.f, 0.f);
            if (gr < M) {
                if (K % BK == 0 || gk + 3 < K) {
                    v = *(const float4*)&A[(size_t)gr * lda + gk];
                } else {
                    float t0 = (gk + 0 < K) ? A[(size_t)gr * lda + gk + 0] : 0.f;
                    float t1 = (gk + 1 < K) ? A[(size_t)gr * lda + gk + 1] : 0.f;
                    float t2 = (gk + 2 < K) ? A[(size_t)gr * lda + gk + 2] : 0.f;
                    float t3 = (gk + 3 < K) ? A[(size_t)gr * lda + gk + 3] : 0.f;
                    v = make_float4(t0, t1, t2, t3);
                }
            }
            *(float4*)&sA[r * SAS + c4] = v;
        }
        __syncthreads();
#pragma unroll
        for (int kq = 0; kq < BK / 4; ++kq) {
            float a[4][4], w[4][4];
#pragma unroll
            for (int i = 0; i < 4; ++i)
                *(float4*)&a[i][0] = *(const float4*)&sA[(tm4 + i) * SAS + kq * 4];
#pragma unroll
            for (int j = 0; j < 4; ++j)
                *(float4*)&w[j][0] = *(const float4*)&sW[(kq * 4 + j) * 64 + tn4];
#pragma unroll
            for (int i = 0; i < 4; ++i)
#pragma unroll
                for (int k = 0; k < 4; ++k)
#pragma unroll
                    for (int j = 0; j < 4; ++j)
                        acc[i][j] = fmaf(a[i][k], w[k][j], acc[i][j]);
        }
        __syncthreads();
    }

    float4 b = *(const float4*)&bias[n0 + tn4];
#pragma unroll
    for (int i = 0; i < 4; ++i) {
        int gr = brow + tm4 + i;
        if (gr < M) {
            float4 v;
            v.x = acc[i][0] + b.x; v.y = acc[i][1] + b.y;
            v.z = acc[i][2] + b.z; v.w = acc[i][3] + b.w;
            if (ACT == 1) {
                v.x = fmaxf(v.x, 0.f); v.y = fmaxf(v.y, 0.f);
                v.z = fmaxf(v.z, 0.f); v.w = fmaxf(v.w, 0.f);
            }
            *(float4*)&out[(size_t)gr * ldo + n0 + tn4] = v;
        }
    }
}

// ---------------------------------------------------------------------------
// CSR build: zero counts -> histogram dst -> exclusive scan -> fill lists
// ---------------------------------------------------------------------------
__global__ __launch_bounds__(256) void zero_kernel(int* __restrict__ p, int n)
{
    int i = blockIdx.x * 256 + threadIdx.x;
    if (i < n) p[i] = 0;
}

__global__ __launch_bounds__(256) void count_kernel(
    const int* __restrict__ dst, int* __restrict__ counts, int ne)
{
    int e = blockIdx.x * 256 + threadIdx.x;
    if (e < ne) atomicAdd(&counts[dst[e]], 1);
}

__global__ __launch_bounds__(1024) void scan_kernel(
    const int* __restrict__ counts, int* __restrict__ row_ptr,
    int* __restrict__ cursor, int n)
{
    __shared__ int sdata[1024];
    const int t = threadIdx.x;
    const int C = (n + 1023) / 1024;
    const int lo = t * C, hi = min(lo + C, n);
    int s = 0;
    for (int i = lo; i < hi; ++i) s += counts[i];
    sdata[t] = s;
    __syncthreads();
    for (int off = 1; off < 1024; off <<= 1) {
        int v = (t >= off) ? sdata[t - off] : 0;
        __syncthreads();
        sdata[t] += v;
        __syncthreads();
    }
    int run = sdata[t] - s;   // exclusive prefix
    for (int i = lo; i < hi; ++i) {
        int c = counts[i];
        row_ptr[i] = run;
        cursor[i]  = run;
        run += c;
    }
    if (t == 1023) row_ptr[n] = sdata[1023];
}

__global__ __launch_bounds__(256) void fill_kernel(
    const int* __restrict__ src, const int* __restrict__ dst,
    int* __restrict__ cursor, int* __restrict__ elist, int ne)
{
    int e = blockIdx.x * 256 + threadIdx.x;
    if (e < ne) {
        int p = atomicAdd(&cursor[dst[e]], 1);
        elist[p] = src[e];
    }
}

// ---------------------------------------------------------------------------
// Gather aggregation: out[i][:] = sum_{e in CSR(i)} h[elist[e]][:]
// One wave per node; lane = column (D=64) or 2 columns (D=128).
// ---------------------------------------------------------------------------
template<int D>
__global__ __launch_bounds__(256) void agg_kernel(
    const float* __restrict__ h, int ldh,
    const int* __restrict__ row_ptr, const int* __restrict__ elist,
    float* __restrict__ out, int ldo, int n)
{
    const int lane = threadIdx.x & 63;
    const int node = blockIdx.x * 4 + (threadIdx.x >> 6);
    if (node >= n) return;
    const int beg = row_ptr[node], end = row_ptr[node + 1];
    float a0 = 0.f, a1 = 0.f, b0 = 0.f, b1 = 0.f;
    int e = beg;
    for (; e + 1 < end; e += 2) {
        int s0 = elist[e], s1 = elist[e + 1];
        const float* p0 = h + (size_t)s0 * ldh;
        const float* p1 = h + (size_t)s1 * ldh;
        a0 += p0[lane];
        b0 += p1[lane];
        if (D == 128) { a1 += p0[lane + 64]; b1 += p1[lane + 64]; }
    }
    if (e < end) {
        int s0 = elist[e];
        const float* p0 = h + (size_t)s0 * ldh;
        a0 += p0[lane];
        if (D == 128) a1 += p0[lane + 64];
    }
    float* q = out + (size_t)node * ldo;
    q[lane] = a0 + b0;
    if (D == 128) q[lane + 64] = a1 + b1;
}

// ---------------------------------------------------------------------------
// Final: out = sigmoid([X | X1 | X2] @ W2 + b2), K=448, NC=50 (padded to 64)
// Same register-tiled structure; A staged per-chunk from the right buffer.
// ---------------------------------------------------------------------------
__global__ __launch_bounds__(256) void final_kernel(
    const float* __restrict__ X,    // [M,64]
    const float* __restrict__ X1,   // [M,128]
    const float* __restrict__ X2,   // [M,256]
    const float* __restrict__ W2,   // [448,50]
    const float* __restrict__ b2,   // [50]
    float* __restrict__ out, int M)
{
    constexpr int BM = 64, BK = 32, NC = 50, SAS = 36;
    __shared__ float sA[BM * SAS];
    __shared__ float sW[BK * 64];
    const int tid  = threadIdx.x;
    const int brow = blockIdx.x * BM;
    const int tn4  = (tid & 15) * 4;
    const int tm4  = (tid >> 4) * 4;

    float acc[4][4];
#pragma unroll
    for (int i = 0; i < 4; ++i)
#pragma unroll
        for (int j = 0; j < 4; ++j) acc[i][j] = 0.f;

    for (int ch = 0; ch < 14; ++ch) {          // 14 chunks of 32 = 448
        const float* Ap; int lda, off;
        if (ch < 2)      { Ap = X;  lda = 64;  off = ch * 32; }
        else if (ch < 6) { Ap = X1; lda = 128; off = (ch - 2) * 32; }
        else             { Ap = X2; lda = 256; off = (ch - 6) * 32; }

        // stage W2 chunk [32 x 64] (cols >= 50 zero); scalar (ld 50 unaligned)
        for (int i = tid; i < BK * 64; i += 256) {
            int kk = i >> 6, c = i & 63;
            int gk = ch * 32 + kk;
            sW[i] = (c < NC) ? W2[gk * NC + c] : 0.f;
        }
#pragma unroll
        for (int i = 0; i < 2; ++i) {
            int f = i * 256 + tid;
            int r = f >> 3, c4 = (f & 7) * 4;
            int gr = brow + r;
            float4 v = make_float4(0.f, 0.f, 0.f, 0.f);
            if (gr < M) v = *(const float4*)&Ap[(size_t)gr * lda + off + c4];
            *(float4*)&sA[r * SAS + c4] = v;
        }
        __syncthreads();
#pragma unroll
        for (int kq = 0; kq < BK / 4; ++kq) {
            float a[4][4], w[4][4];
#pragma unroll
            for (int i = 0; i < 4; ++i)
                *(float4*)&a[i][0] = *(const float4*)&sA[(tm4 + i) * SAS + kq * 4];
#pragma unroll
            for (int j = 0; j < 4; ++j)
                *(float4*)&w[j][0] = *(const float4*)&sW[(kq * 4 + j) * 64 + tn4];
#pragma unroll
            for (int i = 0; i < 4; ++i)
#pragma unroll
                for (int k = 0; k < 4; ++k)
#pragma unroll
                    for (int j = 0; j < 4; ++j)
                        acc[i][j] = fmaf(a[i][k], w[k][j], acc[i][j]);
        }
        __syncthreads();
    }

#pragma unroll
    for (int i = 0; i < 4; ++i) {
        int gr = brow + tm4 + i;
        if (gr < M) {
#pragma unroll
            for (int j = 0; j < 4; ++j) {
                int c = tn4 + j;
                if (c < NC) {
                    float v = acc[i][j] + b2[c];
                    out[(size_t)gr * NC + c] = 1.f / (1.f + expf(-v));
                }
            }
        }
    }
}

// ---------------------------------------------------------------------------
extern "C" void kernel_launch(void* const* d_in, const int* in_sizes, int n_in,
                              void* d_out, int out_size, void* d_ws, size_t ws_size,
                              hipStream_t stream)
{
    const float* features = (const float*)d_in[0];
    const int*   ei       = (const int*)d_in[1];
    const float* W1  = (const float*)d_in[2];
    const float* b1  = (const float*)d_in[3];
    const float* Wc1 = (const float*)d_in[4];
    const float* bc1 = (const float*)d_in[5];
    const float* Wc2 = (const float*)d_in[6];
    const float* bc2 = (const float*)d_in[7];
    const float* W2  = (const float*)d_in[8];
    const float* b2  = (const float*)d_in[9];
    float* out = (float*)d_out;

    const int* src = ei;            // edge_index[0]
    const int* dst = ei + N_EDGES;  // edge_index[1]

    // workspace layout (floats)
    float* X  = (float*)d_ws;                 // [N,64]   x
    float* X1 = X  + (size_t)N_NODES * 64;    // [N,128]  concat(x11,x12)
    float* X2 = X1 + (size_t)N_NODES * 128;   // [N,256]  concat(x21,x22)
    float* G  = X2 + (size_t)N_NODES * 256;   // [N,128]  aggregation scratch
    int* counts  = (int*)(G + (size_t)N_NODES * 128);
    int* cursor  = counts + N_NODES;
    int* row_ptr = cursor + N_NODES;          // [N+1]
    int* elist   = row_ptr + (N_NODES + 1);   // [E]

    const int MB = (N_NODES + 63) / 64;       // 782 row-tiles
    const int EB = (N_EDGES + 255) / 256;
    const int NB = (N_NODES + 255) / 256;
    const int AB = (N_NODES + 3) / 4;

    // ---- CSR build (dst-sorted incoming edge lists) ----
    zero_kernel<<<NB, 256, 0, stream>>>(counts, N_NODES);
    count_kernel<<<EB, 256, 0, stream>>>(dst, counts, N_EDGES);
    scan_kernel<<<1, 1024, 0, stream>>>(counts, row_ptr, cursor, N_NODES);
    fill_kernel<<<EB, 256, 0, stream>>>(src, dst, cursor, elist, N_EDGES);

    // ---- x = relu(features @ W1 + b1) ----
    gemm_rt_kernel<500, 1><<<dim3(MB, 1), 256, 0, stream>>>(
        features, 500, W1, 64, b1, X, 64, N_NODES);

    // ---- x11 = A(x) @ Wc1 + bc1 ----
    agg_kernel<64><<<AB, 256, 0, stream>>>(X, 64, row_ptr, elist, G, 128, N_NODES);
    gemm_rt_kernel<64, 0><<<dim3(MB, 1), 256, 0, stream>>>(
        G, 128, Wc1, 64, bc1, X1, 128, N_NODES);

    // ---- x12 = A(x11) @ Wc1 + bc1 ; keep G[:,0:64] = A(x11) for x21 ----
    agg_kernel<64><<<AB, 256, 0, stream>>>(X1, 128, row_ptr, elist, G, 128, N_NODES);
    gemm_rt_kernel<64, 0><<<dim3(MB, 1), 256, 0, stream>>>(
        G, 128, Wc1, 64, bc1, X1 + 64, 128, N_NODES);

    // ---- G[:,64:128] = A(x12) ; x21 = [A(x11)|A(x12)] @ Wc2 + bc2 ----
    agg_kernel<64><<<AB, 256, 0, stream>>>(X1 + 64, 128, row_ptr, elist, G + 64, 128, N_NODES);
    gemm_rt_kernel<128, 0><<<dim3(MB, 2), 256, 0, stream>>>(
        G, 128, Wc2, 128, bc2, X2, 256, N_NODES);

    // ---- G = A(x21) ; x22 = G @ Wc2 + bc2 ----
    agg_kernel<128><<<AB, 256, 0, stream>>>(X2, 256, row_ptr, elist, G, 128, N_NODES);
    gemm_rt_kernel<128, 0><<<dim3(MB, 2), 256, 0, stream>>>(
        G, 128, Wc2, 128, bc2, X2 + 128, 256, N_NODES);

    // ---- out = sigmoid([X | X1 | X2] @ W2 + b2) ----
    final_kernel<<<MB, 256, 0, stream>>>(X, X1, X2, W2, b2, out, N_NODES);
}

// Round 5
// 604.610 us; speedup vs baseline: 3.4555x; 1.2402x over previous
//
#include <hip/hip_runtime.h>
#include <math.h>

#define N_NODES 50000
#define N_EDGES 800000

// ---------------------------------------------------------------------------
// Register-tiled GEMM: out[M, 64*gridDim.y] = act(A[M,K](lda) @ W[K,ldw] + bias)
// BM=64, BN=64, BK=32, 256 threads = 16x16, 4x4 micro-tile per thread.
// ACT: 0=none, 1=relu.
// ---------------------------------------------------------------------------
template<int K, int ACT>
__global__ __launch_bounds__(256) void gemm_rt_kernel(
    const float* __restrict__ A, int lda,
    const float* __restrict__ W, int ldw,
    const float* __restrict__ bias,
    float* __restrict__ out, int ldo, int M)
{
    constexpr int BM = 64, BK = 32;
    constexpr int SAS = 36;                     // sA row stride (pad 32->36)
    constexpr int NCH = (K + BK - 1) / BK;
    __shared__ float sA[BM * SAS];
    __shared__ float sW[BK * 64];
    const int tid  = threadIdx.x;
    const int brow = blockIdx.x * BM;
    const int n0   = blockIdx.y * 64;
    const int tn4  = (tid & 15) * 4;
    const int tm4  = (tid >> 4) * 4;

    float acc[4][4];
#pragma unroll
    for (int i = 0; i < 4; ++i)
#pragma unroll
        for (int j = 0; j < 4; ++j) acc[i][j] = 0.f;

    for (int ch = 0; ch < NCH; ++ch) {
        const int k0 = ch * BK;
#pragma unroll
        for (int i = 0; i < 2; ++i) {
            int f = i * 256 + tid;
            int kk = f >> 4, c4 = (f & 15) * 4;
            int gk = k0 + kk;
            float4 v = make_float4(0.f, 0.f, 0.f, 0.f);
            if (gk < K) v = *(const float4*)&W[(size_t)gk * ldw + n0 + c4];
            *(float4*)&sW[kk * 64 + c4] = v;
        }
#pragma unroll
        for (int i = 0; i < 2; ++i) {
            int f = i * 256 + tid;
            int r = f >> 3, c4 = (f & 7) * 4;
            int gr = brow + r, gk = k0 + c4;
            float4 v = make_float4(0.f, 0.f, 0.f, 0.f);
            if (gr < M) {
                if (K % BK == 0 || gk + 3 < K) {
                    v = *(const float4*)&A[(size_t)gr * lda + gk];
                } else {
                    float t0 = (gk + 0 < K) ? A[(size_t)gr * lda + gk + 0] : 0.f;
                    float t1 = (gk + 1 < K) ? A[(size_t)gr * lda + gk + 1] : 0.f;
                    float t2 = (gk + 2 < K) ? A[(size_t)gr * lda + gk + 2] : 0.f;
                    float t3 = (gk + 3 < K) ? A[(size_t)gr * lda + gk + 3] : 0.f;
                    v = make_float4(t0, t1, t2, t3);
                }
            }
            *(float4*)&sA[r * SAS + c4] = v;
        }
        __syncthreads();
#pragma unroll
        for (int kq = 0; kq < BK / 4; ++kq) {
            float a[4][4], w[4][4];
#pragma unroll
            for (int i = 0; i < 4; ++i)
                *(float4*)&a[i][0] = *(const float4*)&sA[(tm4 + i) * SAS + kq * 4];
#pragma unroll
            for (int j = 0; j < 4; ++j)
                *(float4*)&w[j][0] = *(const float4*)&sW[(kq * 4 + j) * 64 + tn4];
#pragma unroll
            for (int i = 0; i < 4; ++i)
#pragma unroll
                for (int k = 0; k < 4; ++k)
#pragma unroll
                    for (int j = 0; j < 4; ++j)
                        acc[i][j] = fmaf(a[i][k], w[k][j], acc[i][j]);
        }
        __syncthreads();
    }

    float4 b = *(const float4*)&bias[n0 + tn4];
#pragma unroll
    for (int i = 0; i < 4; ++i) {
        int gr = brow + tm4 + i;
        if (gr < M) {
            float4 v;
            v.x = acc[i][0] + b.x; v.y = acc[i][1] + b.y;
            v.z = acc[i][2] + b.z; v.w = acc[i][3] + b.w;
            if (ACT == 1) {
                v.x = fmaxf(v.x, 0.f); v.y = fmaxf(v.y, 0.f);
                v.z = fmaxf(v.z, 0.f); v.w = fmaxf(v.w, 0.f);
            }
            *(float4*)&out[(size_t)gr * ldo + n0 + tn4] = v;
        }
    }
}

// ---------------------------------------------------------------------------
// CSR build: zero -> histogram -> hierarchical scan (3 kernels) -> fill
// ---------------------------------------------------------------------------
__global__ __launch_bounds__(256) void zero_kernel(int* __restrict__ p, int n)
{
    int i = blockIdx.x * 256 + threadIdx.x;
    if (i < n) p[i] = 0;
}

__global__ __launch_bounds__(256) void count_kernel(
    const int* __restrict__ dst, int* __restrict__ counts, int ne)
{
    int e = blockIdx.x * 256 + threadIdx.x;
    if (e < ne) atomicAdd(&counts[dst[e]], 1);
}

// phase 1: per-block exclusive scan of 256 counts; block sum out
__global__ __launch_bounds__(256) void scan1_kernel(
    const int* __restrict__ counts, int* __restrict__ local,
    int* __restrict__ bsum, int n)
{
    __shared__ int sd[256];
    const int t = threadIdx.x;
    const int i = blockIdx.x * 256 + t;
    int c = (i < n) ? counts[i] : 0;
    sd[t] = c;
    __syncthreads();
#pragma unroll
    for (int off = 1; off < 256; off <<= 1) {
        int v = (t >= off) ? sd[t - off] : 0;
        __syncthreads();
        sd[t] += v;
        __syncthreads();
    }
    if (i < n) local[i] = sd[t] - c;           // exclusive prefix within block
    if (t == 255) bsum[blockIdx.x] = sd[255];
}

// phase 2: single block scans the (<=256) block sums -> exclusive offsets
__global__ __launch_bounds__(256) void scan2_kernel(
    const int* __restrict__ bsum, int* __restrict__ boff, int nb)
{
    __shared__ int sd[256];
    const int t = threadIdx.x;
    int v = (t < nb) ? bsum[t] : 0;
    sd[t] = v;
    __syncthreads();
#pragma unroll
    for (int off = 1; off < 256; off <<= 1) {
        int u = (t >= off) ? sd[t - off] : 0;
        __syncthreads();
        sd[t] += u;
        __syncthreads();
    }
    if (t < nb) boff[t] = sd[t] - v;
}

// phase 3: row_ptr[i] = local[i] + boff[block]; cursor = row_ptr; row_ptr[n]=E
__global__ __launch_bounds__(256) void scan3_kernel(
    int* __restrict__ row_ptr, const int* __restrict__ boff,
    int* __restrict__ cursor, int n, int total)
{
    const int i = blockIdx.x * 256 + threadIdx.x;
    if (i < n) {
        int v = row_ptr[i] + boff[blockIdx.x];
        row_ptr[i] = v;
        cursor[i]  = v;
    }
    if (i == 0) row_ptr[n] = total;
}

__global__ __launch_bounds__(256) void fill_kernel(
    const int* __restrict__ src, const int* __restrict__ dst,
    int* __restrict__ cursor, int* __restrict__ elist, int ne)
{
    int e = blockIdx.x * 256 + threadIdx.x;
    if (e < ne) {
        int p = atomicAdd(&cursor[dst[e]], 1);
        elist[p] = src[e];
    }
}

// ---------------------------------------------------------------------------
// Gather aggregation: out[i][:] = sum_{e in CSR(i)} h[elist[e]][:]
// One wave per node; lanes read float4 -> wave covers EPI edges concurrently
// (D=64: 16 lanes/row, 4 edges; D=128: 32 lanes/row, 2 edges), then
// __shfl_xor cross-group reduce.
// ---------------------------------------------------------------------------
template<int D>
__global__ __launch_bounds__(256) void agg_kernel(
    const float* __restrict__ h, int ldh,
    const int* __restrict__ row_ptr, const int* __restrict__ elist,
    float* __restrict__ out, int ldo, int n)
{
    constexpr int LPR = D / 4;                 // lanes per row (16 or 32)
    constexpr int EPI = 64 / LPR;              // edges in flight (4 or 2)
    const int lane = threadIdx.x & 63;
    const int node = blockIdx.x * 4 + (threadIdx.x >> 6);
    if (node >= n) return;
    const int g  = lane / LPR;                 // edge group
    const int c4 = (lane % LPR) * 4;           // column quad
    const int beg = row_ptr[node], end = row_ptr[node + 1];

    float4 acc = make_float4(0.f, 0.f, 0.f, 0.f);
    for (int e = beg + g; e < end; e += EPI) {
        int s = elist[e];
        float4 v = *(const float4*)&h[(size_t)s * ldh + c4];
        acc.x += v.x; acc.y += v.y; acc.z += v.z; acc.w += v.w;
    }
    // reduce across edge groups
    if (EPI == 4) {
        acc.x += __shfl_xor(acc.x, 16); acc.y += __shfl_xor(acc.y, 16);
        acc.z += __shfl_xor(acc.z, 16); acc.w += __shfl_xor(acc.w, 16);
    }
    acc.x += __shfl_xor(acc.x, 32); acc.y += __shfl_xor(acc.y, 32);
    acc.z += __shfl_xor(acc.z, 32); acc.w += __shfl_xor(acc.w, 32);

    if (g == 0)
        *(float4*)&out[(size_t)node * ldo + c4] = acc;
}

// ---------------------------------------------------------------------------
// Final: out = sigmoid([X | X1 | X2] @ W2 + b2), K=448, NC=50 (padded to 64)
// ---------------------------------------------------------------------------
__global__ __launch_bounds__(256) void final_kernel(
    const float* __restrict__ X,    // [M,64]
    const float* __restrict__ X1,   // [M,128]
    const float* __restrict__ X2,   // [M,256]
    const float* __restrict__ W2,   // [448,50]
    const float* __restrict__ b2,   // [50]
    float* __restrict__ out, int M)
{
    constexpr int BM = 64, BK = 32, NC = 50, SAS = 36;
    __shared__ float sA[BM * SAS];
    __shared__ float sW[BK * 64];
    const int tid  = threadIdx.x;
    const int brow = blockIdx.x * BM;
    const int tn4  = (tid & 15) * 4;
    const int tm4  = (tid >> 4) * 4;

    float acc[4][4];
#pragma unroll
    for (int i = 0; i < 4; ++i)
#pragma unroll
        for (int j = 0; j < 4; ++j) acc[i][j] = 0.f;

    for (int ch = 0; ch < 14; ++ch) {          // 14 chunks of 32 = 448
        const float* Ap; int lda, off;
        if (ch < 2)      { Ap = X;  lda = 64;  off = ch * 32; }
        else if (ch < 6) { Ap = X1; lda = 128; off = (ch - 2) * 32; }
        else             { Ap = X2; lda = 256; off = (ch - 6) * 32; }

        for (int i = tid; i < BK * 64; i += 256) {
            int kk = i >> 6, c = i & 63;
            int gk = ch * 32 + kk;
            sW[i] = (c < NC) ? W2[gk * NC + c] : 0.f;
        }
#pragma unroll
        for (int i = 0; i < 2; ++i) {
            int f = i * 256 + tid;
            int r = f >> 3, c4 = (f & 7) * 4;
            int gr = brow + r;
            float4 v = make_float4(0.f, 0.f, 0.f, 0.f);
            if (gr < M) v = *(const float4*)&Ap[(size_t)gr * lda + off + c4];
            *(float4*)&sA[r * SAS + c4] = v;
        }
        __syncthreads();
#pragma unroll
        for (int kq = 0; kq < BK / 4; ++kq) {
            float a[4][4], w[4][4];
#pragma unroll
            for (int i = 0; i < 4; ++i)
                *(float4*)&a[i][0] = *(const float4*)&sA[(tm4 + i) * SAS + kq * 4];
#pragma unroll
            for (int j = 0; j < 4; ++j)
                *(float4*)&w[j][0] = *(const float4*)&sW[(kq * 4 + j) * 64 + tn4];
#pragma unroll
            for (int i = 0; i < 4; ++i)
#pragma unroll
                for (int k = 0; k < 4; ++k)
#pragma unroll
                    for (int j = 0; j < 4; ++j)
                        acc[i][j] = fmaf(a[i][k], w[k][j], acc[i][j]);
        }
        __syncthreads();
    }

#pragma unroll
    for (int i = 0; i < 4; ++i) {
        int gr = brow + tm4 + i;
        if (gr < M) {
#pragma unroll
            for (int j = 0; j < 4; ++j) {
                int c = tn4 + j;
                if (c < NC) {
                    float v = acc[i][j] + b2[c];
                    out[(size_t)gr * NC + c] = 1.f / (1.f + expf(-v));
                }
            }
        }
    }
}

// ---------------------------------------------------------------------------
extern "C" void kernel_launch(void* const* d_in, const int* in_sizes, int n_in,
                              void* d_out, int out_size, void* d_ws, size_t ws_size,
                              hipStream_t stream)
{
    const float* features = (const float*)d_in[0];
    const int*   ei       = (const int*)d_in[1];
    const float* W1  = (const float*)d_in[2];
    const float* b1  = (const float*)d_in[3];
    const float* Wc1 = (const float*)d_in[4];
    const float* bc1 = (const float*)d_in[5];
    const float* Wc2 = (const float*)d_in[6];
    const float* bc2 = (const float*)d_in[7];
    const float* W2  = (const float*)d_in[8];
    const float* b2  = (const float*)d_in[9];
    float* out = (float*)d_out;

    const int* src = ei;            // edge_index[0]
    const int* dst = ei + N_EDGES;  // edge_index[1]

    // workspace layout (floats)
    float* X  = (float*)d_ws;                 // [N,64]   x
    float* X1 = X  + (size_t)N_NODES * 64;    // [N,128]  concat(x11,x12)
    float* X2 = X1 + (size_t)N_NODES * 128;   // [N,256]  concat(x21,x22)
    float* G  = X2 + (size_t)N_NODES * 256;   // [N,128]  aggregation scratch
    int* counts  = (int*)(G + (size_t)N_NODES * 128);
    int* cursor  = counts + N_NODES;
    int* row_ptr = cursor + N_NODES;          // [N+1]
    int* elist   = row_ptr + (N_NODES + 1);   // [E]
    int* bsum    = elist + N_EDGES;           // [<=256]
    int* boff    = bsum + 256;                // [<=256]

    const int MB = (N_NODES + 63) / 64;       // 782 row-tiles
    const int EB = (N_EDGES + 255) / 256;
    const int NB = (N_NODES + 255) / 256;     // 196 (<= 256 for scan2)
    const int AB = (N_NODES + 3) / 4;

    // ---- CSR build (dst-sorted incoming edge lists) ----
    zero_kernel<<<NB, 256, 0, stream>>>(counts, N_NODES);
    count_kernel<<<EB, 256, 0, stream>>>(dst, counts, N_EDGES);
    scan1_kernel<<<NB, 256, 0, stream>>>(counts, row_ptr, bsum, N_NODES);
    scan2_kernel<<<1, 256, 0, stream>>>(bsum, boff, NB);
    scan3_kernel<<<NB, 256, 0, stream>>>(row_ptr, boff, cursor, N_NODES, N_EDGES);
    fill_kernel<<<EB, 256, 0, stream>>>(src, dst, cursor, elist, N_EDGES);

    // ---- x = relu(features @ W1 + b1) ----
    gemm_rt_kernel<500, 1><<<dim3(MB, 1), 256, 0, stream>>>(
        features, 500, W1, 64, b1, X, 64, N_NODES);

    // ---- x11 = A(x) @ Wc1 + bc1 ----
    agg_kernel<64><<<AB, 256, 0, stream>>>(X, 64, row_ptr, elist, G, 128, N_NODES);
    gemm_rt_kernel<64, 0><<<dim3(MB, 1), 256, 0, stream>>>(
        G, 128, Wc1, 64, bc1, X1, 128, N_NODES);

    // ---- x12 = A(x11) @ Wc1 + bc1 ; keep G[:,0:64] = A(x11) for x21 ----
    agg_kernel<64><<<AB, 256, 0, stream>>>(X1, 128, row_ptr, elist, G, 128, N_NODES);
    gemm_rt_kernel<64, 0><<<dim3(MB, 1), 256, 0, stream>>>(
        G, 128, Wc1, 64, bc1, X1 + 64, 128, N_NODES);

    // ---- G[:,64:128] = A(x12) ; x21 = [A(x11)|A(x12)] @ Wc2 + bc2 ----
    agg_kernel<64><<<AB, 256, 0, stream>>>(X1 + 64, 128, row_ptr, elist, G + 64, 128, N_NODES);
    gemm_rt_kernel<128, 0><<<dim3(MB, 2), 256, 0, stream>>>(
        G, 128, Wc2, 128, bc2, X2, 256, N_NODES);

    // ---- G = A(x21) ; x22 = G @ Wc2 + bc2 ----
    agg_kernel<128><<<AB, 256, 0, stream>>>(X2, 256, row_ptr, elist, G, 128, N_NODES);
    gemm_rt_kernel<128, 0><<<dim3(MB, 2), 256, 0, stream>>>(
        G, 128, Wc2, 128, bc2, X2 + 128, 256, N_NODES);

    // ---- out = sigmoid([X | X1 | X2] @ W2 + b2) ----
    final_kernel<<<MB, 256, 0, stream>>>(X, X1, X2, W2, b2, out, N_NODES);
}

// Round 7
// 575.981 us; speedup vs baseline: 3.6273x; 1.0497x over previous
//
#include <hip/hip_runtime.h>
#include <math.h>

#define N_NODES 50000
#define N_EDGES 800000

typedef short bf16x8 __attribute__((ext_vector_type(8)));
typedef float f32x4 __attribute__((ext_vector_type(4)));

// ---- exact bf16 split helpers (bit-level RN-even, no HW cvt needed) ----
__device__ __forceinline__ ushort f2bf(float f) {
    unsigned u = __float_as_uint(f);
    u += 0x7fffu + ((u >> 16) & 1u);
    return (ushort)(u >> 16);
}
__device__ __forceinline__ float bf2f(ushort h) {
    return __uint_as_float(((unsigned)h) << 16);
}
__device__ __forceinline__ void split2(float a, ushort& h, ushort& l) {
    h = f2bf(a);
    l = f2bf(a - bf2f(h));
}

// ---------------------------------------------------------------------------
// Weight convert+transpose: W[K][N] f32 -> WThi/WTlo[NP][KP] bf16 (zero-pad)
// ---------------------------------------------------------------------------
__global__ __launch_bounds__(256) void convert_wt_kernel(
    const float* __restrict__ W, int K, int N, int KP, int NP,
    ushort* __restrict__ Th, ushort* __restrict__ Tl)
{
    int i = blockIdx.x * 256 + threadIdx.x;
    if (i >= NP * KP) return;
    int n = i / KP, k = i % KP;
    float v = (k < K && n < N) ? W[(size_t)k * N + n] : 0.f;
    ushort h, l;
    split2(v, h, l);
    Th[(size_t)n * KP + k] = h;
    Tl[(size_t)n * KP + k] = l;
}

// ---------------------------------------------------------------------------
// Shared MFMA-GEMM pieces. Block = 256 thr = 4 waves; tile BM=128 x BN=64;
// wave tile 64x32 (4x2 mfma 16x16x32 frags); 3 products (hh, hl, lh).
// LDS rows padded to 40 k-slots (80 B) -> frag b128 reads are 2-way max.
// ---------------------------------------------------------------------------
__device__ __forceinline__ void stage_B_lds(
    const ushort* __restrict__ WTh, const ushort* __restrict__ WTl,
    int n0, int KP, int k0, ushort* sBh, ushort* sBl, int tid)
{
    for (int i = tid; i < 512; i += 256) {
        int pl = i >> 8, s = i & 255, row = s >> 2, q = s & 3;
        const ushort* src = pl ? WTl : WTh;
        uint4 v = *(const uint4*)&src[(size_t)(n0 + row) * KP + k0 + q * 8];
        ushort* d = pl ? sBl : sBh;
        *(uint4*)&d[row * 40 + q * 8] = v;
    }
}

__device__ __forceinline__ void stage_A_planes(
    const ushort* __restrict__ Ahi, const ushort* __restrict__ Alo,
    int lda, int brow, int M, int k0, ushort* sAh, ushort* sAl, int tid)
{
    for (int i = tid; i < 1024; i += 256) {
        int pl = i >> 9, s = i & 511, row = s >> 2, q = s & 3;
        int gr = brow + row;
        uint4 v = make_uint4(0u, 0u, 0u, 0u);
        const ushort* src = pl ? Alo : Ahi;
        if (gr < M) v = *(const uint4*)&src[(size_t)gr * lda + k0 + q * 8];
        ushort* d = pl ? sAl : sAh;
        *(uint4*)&d[row * 40 + q * 8] = v;
    }
}

__device__ __forceinline__ void mfma_compute(
    const ushort* sAh, const ushort* sAl,
    const ushort* sBh, const ushort* sBl,
    int lane, int wr, int wc, f32x4 acc[4][2])
{
    bf16x8 ah[4], al[4], bh[2], bl[2];
#pragma unroll
    for (int mi = 0; mi < 4; ++mi) {
        int off = (wr + mi * 16 + (lane & 15)) * 40 + (lane >> 4) * 8;
        ah[mi] = *(const bf16x8*)&sAh[off];
        al[mi] = *(const bf16x8*)&sAl[off];
    }
#pragma unroll
    for (int ni = 0; ni < 2; ++ni) {
        int off = (wc + ni * 16 + (lane & 15)) * 40 + (lane >> 4) * 8;
        bh[ni] = *(const bf16x8*)&sBh[off];
        bl[ni] = *(const bf16x8*)&sBl[off];
    }
#pragma unroll
    for (int mi = 0; mi < 4; ++mi)
#pragma unroll
        for (int ni = 0; ni < 2; ++ni) {
            acc[mi][ni] = __builtin_amdgcn_mfma_f32_16x16x32_bf16(ah[mi], bh[ni], acc[mi][ni], 0, 0, 0);
            acc[mi][ni] = __builtin_amdgcn_mfma_f32_16x16x32_bf16(ah[mi], bl[ni], acc[mi][ni], 0, 0, 0);
            acc[mi][ni] = __builtin_amdgcn_mfma_f32_16x16x32_bf16(al[mi], bh[ni], acc[mi][ni], 0, 0, 0);
        }
}

// ---------------------------------------------------------------------------
// GEMM on pre-split planes: O = A @ W + bias, output split-stored.
// A planes [M][lda]; WT planes [N][K] (K mult of 32). ACT: 1 = relu.
// ---------------------------------------------------------------------------
template<int K, int ACT>
__global__ __launch_bounds__(256) void gemm_mfma_kernel(
    const ushort* __restrict__ Ahi, const ushort* __restrict__ Alo, int lda,
    const ushort* __restrict__ WTh, const ushort* __restrict__ WTl,
    const float* __restrict__ bias,
    ushort* __restrict__ Ohi, ushort* __restrict__ Olo, int ldo, int M)
{
    __shared__ ushort sAh[128 * 40], sAl[128 * 40], sBh[64 * 40], sBl[64 * 40];
    const int tid  = threadIdx.x;
    const int brow = blockIdx.x * 128;
    const int n0   = blockIdx.y * 64;
    const int lane = tid & 63, w = tid >> 6;
    const int wr = (w >> 1) * 64, wc = (w & 1) * 32;

    f32x4 acc[4][2];
#pragma unroll
    for (int mi = 0; mi < 4; ++mi)
#pragma unroll
        for (int ni = 0; ni < 2; ++ni) acc[mi][ni] = (f32x4)0.f;

    for (int ch = 0; ch < K / 32; ++ch) {
        const int k0 = ch * 32;
        stage_A_planes(Ahi, Alo, lda, brow, M, k0, sAh, sAl, tid);
        stage_B_lds(WTh, WTl, n0, K, k0, sBh, sBl, tid);
        __syncthreads();
        mfma_compute(sAh, sAl, sBh, sBl, lane, wr, wc, acc);
        __syncthreads();
    }

#pragma unroll
    for (int mi = 0; mi < 4; ++mi)
#pragma unroll
        for (int ni = 0; ni < 2; ++ni) {
            int col = n0 + wc + ni * 16 + (lane & 15);
            float b = bias[col];
#pragma unroll
            for (int r = 0; r < 4; ++r) {
                int row = brow + wr + mi * 16 + (lane >> 4) * 4 + r;
                if (row < M) {
                    float v = acc[mi][ni][r] + b;
                    if (ACT == 1) v = fmaxf(v, 0.f);
                    ushort h, l;
                    split2(v, h, l);
                    Ohi[(size_t)row * ldo + col] = h;
                    Olo[(size_t)row * ldo + col] = l;
                }
            }
        }
}

// ---------------------------------------------------------------------------
// First layer: A = features f32 [M][500] (split inline), W1T planes [64][512],
// relu, split-store X planes.
// ---------------------------------------------------------------------------
__global__ __launch_bounds__(256) void gemm_feat_kernel(
    const float* __restrict__ A,
    const ushort* __restrict__ WTh, const ushort* __restrict__ WTl,
    const float* __restrict__ bias,
    ushort* __restrict__ Ohi, ushort* __restrict__ Olo, int M)
{
    __shared__ ushort sAh[128 * 40], sAl[128 * 40], sBh[64 * 40], sBl[64 * 40];
    const int tid  = threadIdx.x;
    const int brow = blockIdx.x * 128;
    const int lane = tid & 63, w = tid >> 6;
    const int wr = (w >> 1) * 64, wc = (w & 1) * 32;

    f32x4 acc[4][2];
#pragma unroll
    for (int mi = 0; mi < 4; ++mi)
#pragma unroll
        for (int ni = 0; ni < 2; ++ni) acc[mi][ni] = (f32x4)0.f;

    for (int ch = 0; ch < 16; ++ch) {           // KP = 512
        const int k0 = ch * 32;
        // stage+split A: 128 rows x 8 quads of 4 floats
        for (int i = tid; i < 1024; i += 256) {
            int row = i >> 3, q = i & 7;
            int gr = brow + row, gk = k0 + q * 4;
            float4 v = make_float4(0.f, 0.f, 0.f, 0.f);
            if (gr < M) {
                const float* ap = A + (size_t)gr * 500;
                if (gk + 3 < 500) {
                    v = *(const float4*)&ap[gk];
                } else {
                    if (gk + 0 < 500) v.x = ap[gk + 0];
                    if (gk + 1 < 500) v.y = ap[gk + 1];
                    if (gk + 2 < 500) v.z = ap[gk + 2];
                    if (gk + 3 < 500) v.w = ap[gk + 3];
                }
            }
            ushort h0, h1, h2, h3, l0, l1, l2, l3;
            split2(v.x, h0, l0); split2(v.y, h1, l1);
            split2(v.z, h2, l2); split2(v.w, h3, l3);
            uint2 hv, lv;
            hv.x = (unsigned)h0 | ((unsigned)h1 << 16);
            hv.y = (unsigned)h2 | ((unsigned)h3 << 16);
            lv.x = (unsigned)l0 | ((unsigned)l1 << 16);
            lv.y = (unsigned)l2 | ((unsigned)l3 << 16);
            *(uint2*)&sAh[row * 40 + q * 4] = hv;
            *(uint2*)&sAl[row * 40 + q * 4] = lv;
        }
        stage_B_lds(WTh, WTl, 0, 512, k0, sBh, sBl, tid);
        __syncthreads();
        mfma_compute(sAh, sAl, sBh, sBl, lane, wr, wc, acc);
        __syncthreads();
    }

#pragma unroll
    for (int mi = 0; mi < 4; ++mi)
#pragma unroll
        for (int ni = 0; ni < 2; ++ni) {
            int col = wc + ni * 16 + (lane & 15);
            float b = bias[col];
#pragma unroll
            for (int r = 0; r < 4; ++r) {
                int row = brow + wr + mi * 16 + (lane >> 4) * 4 + r;
                if (row < M) {
                    float v = fmaxf(acc[mi][ni][r] + b, 0.f);
                    ushort h, l;
                    split2(v, h, l);
                    Ohi[(size_t)row * 64 + col] = h;
                    Olo[(size_t)row * 64 + col] = l;
                }
            }
        }
}

// ---------------------------------------------------------------------------
// Final: out = sigmoid([X|X1|X2] @ W2 + b2) fp32, K=448, cols 0..49.
// ---------------------------------------------------------------------------
__global__ __launch_bounds__(256) void final_mfma_kernel(
    const ushort* __restrict__ Xhi,  const ushort* __restrict__ Xlo,
    const ushort* __restrict__ X1hi, const ushort* __restrict__ X1lo,
    const ushort* __restrict__ X2hi, const ushort* __restrict__ X2lo,
    const ushort* __restrict__ WTh,  const ushort* __restrict__ WTl,
    const float* __restrict__ b2,
    float* __restrict__ out, int M)
{
    __shared__ ushort sAh[128 * 40], sAl[128 * 40], sBh[64 * 40], sBl[64 * 40];
    const int tid  = threadIdx.x;
    const int brow = blockIdx.x * 128;
    const int lane = tid & 63, w = tid >> 6;
    const int wr = (w >> 1) * 64, wc = (w & 1) * 32;

    f32x4 acc[4][2];
#pragma unroll
    for (int mi = 0; mi < 4; ++mi)
#pragma unroll
        for (int ni = 0; ni < 2; ++ni) acc[mi][ni] = (f32x4)0.f;

    for (int ch = 0; ch < 14; ++ch) {
        const ushort *Ah, *Al;
        int lda, off;
        if (ch < 2)      { Ah = Xhi;  Al = Xlo;  lda = 64;  off = ch * 32; }
        else if (ch < 6) { Ah = X1hi; Al = X1lo; lda = 128; off = (ch - 2) * 32; }
        else             { Ah = X2hi; Al = X2lo; lda = 256; off = (ch - 6) * 32; }
        stage_A_planes(Ah + off, Al + off, lda, brow, M, 0, sAh, sAl, tid);
        stage_B_lds(WTh, WTl, 0, 448, ch * 32, sBh, sBl, tid);
        __syncthreads();
        mfma_compute(sAh, sAl, sBh, sBl, lane, wr, wc, acc);
        __syncthreads();
    }

#pragma unroll
    for (int mi = 0; mi < 4; ++mi)
#pragma unroll
        for (int ni = 0; ni < 2; ++ni) {
            int col = wc + ni * 16 + (lane & 15);
            if (col < 50) {
                float b = b2[col];
#pragma unroll
                for (int r = 0; r < 4; ++r) {
                    int row = brow + wr + mi * 16 + (lane >> 4) * 4 + r;
                    if (row < M) {
                        float v = acc[mi][ni][r] + b;
                        out[(size_t)row * 50 + col] = 1.f / (1.f + expf(-v));
                    }
                }
            }
        }
}

// ---------------------------------------------------------------------------
// CSR build (unchanged from R5)
// ---------------------------------------------------------------------------
__global__ __launch_bounds__(256) void zero_kernel(int* __restrict__ p, int n)
{
    int i = blockIdx.x * 256 + threadIdx.x;
    if (i < n) p[i] = 0;
}

__global__ __launch_bounds__(256) void count_kernel(
    const int* __restrict__ dst, int* __restrict__ counts, int ne)
{
    int e = blockIdx.x * 256 + threadIdx.x;
    if (e < ne) atomicAdd(&counts[dst[e]], 1);
}

__global__ __launch_bounds__(256) void scan1_kernel(
    const int* __restrict__ counts, int* __restrict__ local,
    int* __restrict__ bsum, int n)
{
    __shared__ int sd[256];
    const int t = threadIdx.x;
    const int i = blockIdx.x * 256 + t;
    int c = (i < n) ? counts[i] : 0;
    sd[t] = c;
    __syncthreads();
#pragma unroll
    for (int off = 1; off < 256; off <<= 1) {
        int v = (t >= off) ? sd[t - off] : 0;
        __syncthreads();
        sd[t] += v;
        __syncthreads();
    }
    if (i < n) local[i] = sd[t] - c;
    if (t == 255) bsum[blockIdx.x] = sd[255];
}

__global__ __launch_bounds__(256) void scan2_kernel(
    const int* __restrict__ bsum, int* __restrict__ boff, int nb)
{
    __shared__ int sd[256];
    const int t = threadIdx.x;
    int v = (t < nb) ? bsum[t] : 0;
    sd[t] = v;
    __syncthreads();
#pragma unroll
    for (int off = 1; off < 256; off <<= 1) {
        int u = (t >= off) ? sd[t - off] : 0;
        __syncthreads();
        sd[t] += u;
        __syncthreads();
    }
    if (t < nb) boff[t] = sd[t] - v;
}

__global__ __launch_bounds__(256) void scan3_kernel(
    int* __restrict__ row_ptr, const int* __restrict__ boff,
    int* __restrict__ cursor, int n, int total)
{
    const int i = blockIdx.x * 256 + threadIdx.x;
    if (i < n) {
        int v = row_ptr[i] + boff[blockIdx.x];
        row_ptr[i] = v;
        cursor[i]  = v;
    }
    if (i == 0) row_ptr[n] = total;
}

__global__ __launch_bounds__(256) void fill_kernel(
    const int* __restrict__ src, const int* __restrict__ dst,
    int* __restrict__ cursor, int* __restrict__ elist, int ne)
{
    int e = blockIdx.x * 256 + threadIdx.x;
    if (e < ne) {
        int p = atomicAdd(&cursor[dst[e]], 1);
        elist[p] = src[e];
    }
}

// ---------------------------------------------------------------------------
// Gather aggregation over split planes: o[i][:] = sum_e (hi+lo)[elist[e]][:]
// fp32 accumulate, split on store. One wave/node, float4-equivalent width.
// ---------------------------------------------------------------------------
template<int D>
__global__ __launch_bounds__(256) void agg_planes_kernel(
    const ushort* __restrict__ hhi, const ushort* __restrict__ hlo, int ldh,
    const int* __restrict__ row_ptr, const int* __restrict__ elist,
    ushort* __restrict__ ohi, ushort* __restrict__ olo, int ldo, int n)
{
    constexpr int LPR = D / 4;                 // lanes per row (16 or 32)
    constexpr int EPI = 64 / LPR;              // edges in flight (4 or 2)
    const int lane = threadIdx.x & 63;
    const int node = blockIdx.x * 4 + (threadIdx.x >> 6);
    if (node >= n) return;
    const int g  = lane / LPR;
    const int c4 = (lane % LPR) * 4;
    const int beg = row_ptr[node], end = row_ptr[node + 1];

    float a0 = 0.f, a1 = 0.f, a2 = 0.f, a3 = 0.f;
    for (int e = beg + g; e < end; e += EPI) {
        int s = elist[e];
        uint2 hv = *(const uint2*)&hhi[(size_t)s * ldh + c4];
        uint2 lv = *(const uint2*)&hlo[(size_t)s * ldh + c4];
        a0 += bf2f((ushort)hv.x) + bf2f((ushort)lv.x);
        a1 += bf2f((ushort)(hv.x >> 16)) + bf2f((ushort)(lv.x >> 16));
        a2 += bf2f((ushort)hv.y) + bf2f((ushort)lv.y);
        a3 += bf2f((ushort)(hv.y >> 16)) + bf2f((ushort)(lv.y >> 16));
    }
    if (EPI == 4) {
        a0 += __shfl_xor(a0, 16); a1 += __shfl_xor(a1, 16);
        a2 += __shfl_xor(a2, 16); a3 += __shfl_xor(a3, 16);
    }
    a0 += __shfl_xor(a0, 32); a1 += __shfl_xor(a1, 32);
    a2 += __shfl_xor(a2, 32); a3 += __shfl_xor(a3, 32);

    if (g == 0) {
        ushort h0, h1, h2, h3, l0, l1, l2, l3;
        split2(a0, h0, l0); split2(a1, h1, l1);
        split2(a2, h2, l2); split2(a3, h3, l3);
        uint2 hv, lv;
        hv.x = (unsigned)h0 | ((unsigned)h1 << 16);
        hv.y = (unsigned)h2 | ((unsigned)h3 << 16);
        lv.x = (unsigned)l0 | ((unsigned)l1 << 16);
        lv.y = (unsigned)l2 | ((unsigned)l3 << 16);
        *(uint2*)&ohi[(size_t)node * ldo + c4] = hv;
        *(uint2*)&olo[(size_t)node * ldo + c4] = lv;
    }
}

// ---------------------------------------------------------------------------
extern "C" void kernel_launch(void* const* d_in, const int* in_sizes, int n_in,
                              void* d_out, int out_size, void* d_ws, size_t ws_size,
                              hipStream_t stream)
{
    const float* features = (const float*)d_in[0];
    const int*   ei       = (const int*)d_in[1];
    const float* W1  = (const float*)d_in[2];
    const float* b1  = (const float*)d_in[3];
    const float* Wc1 = (const float*)d_in[4];
    const float* bc1 = (const float*)d_in[5];
    const float* Wc2 = (const float*)d_in[6];
    const float* bc2 = (const float*)d_in[7];
    const float* W2  = (const float*)d_in[8];
    const float* b2  = (const float*)d_in[9];
    float* out = (float*)d_out;

    const int* src = ei;            // edge_index[0]
    const int* dst = ei + N_EDGES;  // edge_index[1]

    // workspace: bf16 hi/lo planes for all intermediates
    ushort* Xhi  = (ushort*)d_ws;                       // [N][64]
    ushort* Xlo  = Xhi  + (size_t)N_NODES * 64;
    ushort* X1hi = Xlo  + (size_t)N_NODES * 64;         // [N][128]
    ushort* X1lo = X1hi + (size_t)N_NODES * 128;
    ushort* X2hi = X1lo + (size_t)N_NODES * 128;        // [N][256]
    ushort* X2lo = X2hi + (size_t)N_NODES * 256;
    ushort* Ghi  = X2lo + (size_t)N_NODES * 256;        // [N][128] agg scratch
    ushort* Glo  = Ghi  + (size_t)N_NODES * 128;
    ushort* W1Th  = Glo  + (size_t)N_NODES * 128;       // [64][512]
    ushort* W1Tl  = W1Th  + 64 * 512;
    ushort* Wc1Th = W1Tl  + 64 * 512;                   // [64][64]
    ushort* Wc1Tl = Wc1Th + 64 * 64;
    ushort* Wc2Th = Wc1Tl + 64 * 64;                    // [128][128]
    ushort* Wc2Tl = Wc2Th + 128 * 128;
    ushort* W2Th  = Wc2Tl + 128 * 128;                  // [64][448]
    ushort* W2Tl  = W2Th  + 64 * 448;
    int* counts  = (int*)(W2Tl + 64 * 448);
    int* cursor  = counts + N_NODES;
    int* row_ptr = cursor + N_NODES;                    // [N+1]
    int* elist   = row_ptr + (N_NODES + 1);             // [E]
    int* bsum    = elist + N_EDGES;
    int* boff    = bsum + 256;

    const int MB = (N_NODES + 127) / 128;               // 391 row-tiles
    const int EB = (N_EDGES + 255) / 256;
    const int NB = (N_NODES + 255) / 256;               // 196
    const int AB = (N_NODES + 3) / 4;

    // ---- CSR build ----
    zero_kernel<<<NB, 256, 0, stream>>>(counts, N_NODES);
    count_kernel<<<EB, 256, 0, stream>>>(dst, counts, N_EDGES);
    scan1_kernel<<<NB, 256, 0, stream>>>(counts, row_ptr, bsum, N_NODES);
    scan2_kernel<<<1, 256, 0, stream>>>(bsum, boff, NB);
    scan3_kernel<<<NB, 256, 0, stream>>>(row_ptr, boff, cursor, N_NODES, N_EDGES);
    fill_kernel<<<EB, 256, 0, stream>>>(src, dst, cursor, elist, N_EDGES);

    // ---- weight convert+transpose (split bf16) ----
    convert_wt_kernel<<<(64 * 512 + 255) / 256, 256, 0, stream>>>(W1, 500, 64, 512, 64, W1Th, W1Tl);
    convert_wt_kernel<<<(64 * 64 + 255) / 256, 256, 0, stream>>>(Wc1, 64, 64, 64, 64, Wc1Th, Wc1Tl);
    convert_wt_kernel<<<(128 * 128 + 255) / 256, 256, 0, stream>>>(Wc2, 128, 128, 128, 128, Wc2Th, Wc2Tl);
    convert_wt_kernel<<<(64 * 448 + 255) / 256, 256, 0, stream>>>(W2, 448, 50, 448, 64, W2Th, W2Tl);

    // ---- x = relu(features @ W1 + b1) -> X planes ----
    gemm_feat_kernel<<<MB, 256, 0, stream>>>(features, W1Th, W1Tl, b1, Xhi, Xlo, N_NODES);

    // ---- x11 = A(x) @ Wc1 + bc1 -> X1[:,0:64] ----
    agg_planes_kernel<64><<<AB, 256, 0, stream>>>(Xhi, Xlo, 64, row_ptr, elist, Ghi, Glo, 128, N_NODES);
    gemm_mfma_kernel<64, 0><<<dim3(MB, 1), 256, 0, stream>>>(
        Ghi, Glo, 128, Wc1Th, Wc1Tl, bc1, X1hi, X1lo, 128, N_NODES);

    // ---- x12 = A(x11) @ Wc1 + bc1 -> X1[:,64:128]; G[:,0:64] = A(x11) kept ----
    agg_planes_kernel<64><<<AB, 256, 0, stream>>>(X1hi, X1lo, 128, row_ptr, elist, Ghi, Glo, 128, N_NODES);
    gemm_mfma_kernel<64, 0><<<dim3(MB, 1), 256, 0, stream>>>(
        Ghi, Glo, 128, Wc1Th, Wc1Tl, bc1, X1hi + 64, X1lo + 64, 128, N_NODES);

    // ---- G[:,64:128] = A(x12); x21 = [A(x11)|A(x12)] @ Wc2 + bc2 ----
    agg_planes_kernel<64><<<AB, 256, 0, stream>>>(X1hi + 64, X1lo + 64, 128, row_ptr, elist,
                                                  Ghi + 64, Glo + 64, 128, N_NODES);
    gemm_mfma_kernel<128, 0><<<dim3(MB, 2), 256, 0, stream>>>(
        Ghi, Glo, 128, Wc2Th, Wc2Tl, bc2, X2hi, X2lo, 256, N_NODES);

    // ---- G = A(x21); x22 = G @ Wc2 + bc2 -> X2[:,128:256] ----
    agg_planes_kernel<128><<<AB, 256, 0, stream>>>(X2hi, X2lo, 256, row_ptr, elist, Ghi, Glo, 128, N_NODES);
    gemm_mfma_kernel<128, 0><<<dim3(MB, 2), 256, 0, stream>>>(
        Ghi, Glo, 128, Wc2Th, Wc2Tl, bc2, X2hi + 128, X2lo + 128, 256, N_NODES);

    // ---- out = sigmoid([X|X1|X2] @ W2 + b2) ----
    final_mfma_kernel<<<MB, 256, 0, stream>>>(Xhi, Xlo, X1hi, X1lo, X2hi, X2lo,
                                              W2Th, W2Tl, b2, out, N_NODES);
}